// Round 3
// baseline (1731.371 us; speedup 1.0000x reference)
//
#include <hip/hip_runtime.h>
#include <stdint.h>

#define HH 128
#define WW 128
#define CHN 16
#define NPIX (HH*WW)          // 16384 per batch
#define PLANE (CHN*NPIX)      // 262144 per batch
#define STEPS 64
#define TW 8
#define TH 8

__host__ __device__ __forceinline__ uint32_t rotl32_(uint32_t x, int d) {
  return (x << d) | (x >> (32 - d));
}

__host__ __device__ __forceinline__ void tf2x32(uint32_t k0, uint32_t k1,
                                                uint32_t x0, uint32_t x1,
                                                uint32_t* o0, uint32_t* o1) {
  uint32_t ks0 = k0, ks1 = k1, ks2 = k0 ^ k1 ^ 0x1BD11BDAu;
  x0 += ks0; x1 += ks1;
  x0 += x1; x1 = rotl32_(x1, 13); x1 ^= x0;
  x0 += x1; x1 = rotl32_(x1, 15); x1 ^= x0;
  x0 += x1; x1 = rotl32_(x1, 26); x1 ^= x0;
  x0 += x1; x1 = rotl32_(x1, 6);  x1 ^= x0;
  x0 += ks1; x1 += ks2 + 1u;
  x0 += x1; x1 = rotl32_(x1, 17); x1 ^= x0;
  x0 += x1; x1 = rotl32_(x1, 29); x1 ^= x0;
  x0 += x1; x1 = rotl32_(x1, 16); x1 ^= x0;
  x0 += x1; x1 = rotl32_(x1, 24); x1 ^= x0;
  x0 += ks2; x1 += ks0 + 2u;
  x0 += x1; x1 = rotl32_(x1, 13); x1 ^= x0;
  x0 += x1; x1 = rotl32_(x1, 15); x1 ^= x0;
  x0 += x1; x1 = rotl32_(x1, 26); x1 ^= x0;
  x0 += x1; x1 = rotl32_(x1, 6);  x1 ^= x0;
  x0 += ks0; x1 += ks1 + 3u;
  x0 += x1; x1 = rotl32_(x1, 17); x1 ^= x0;
  x0 += x1; x1 = rotl32_(x1, 29); x1 ^= x0;
  x0 += x1; x1 = rotl32_(x1, 16); x1 ^= x0;
  x0 += x1; x1 = rotl32_(x1, 24); x1 ^= x0;
  x0 += ks1; x1 += ks2 + 4u;
  x0 += x1; x1 = rotl32_(x1, 13); x1 ^= x0;
  x0 += x1; x1 = rotl32_(x1, 15); x1 ^= x0;
  x0 += x1; x1 = rotl32_(x1, 26); x1 ^= x0;
  x0 += x1; x1 = rotl32_(x1, 6);  x1 ^= x0;
  x0 += ks2; x1 += ks0 + 5u;
  *o0 = x0; *o1 = x1;
}

// --- prep: transpose w1 (48 x 128) -> w1t (128 x 48)
__global__ void prep_w1t(const float* __restrict__ w1, float* __restrict__ w1t) {
  int i = blockIdx.x * 256 + threadIdx.x;
  if (i < 48 * 128) {
    int j = i / 48, k = i % 48;
    w1t[i] = w1[k * 128 + j];
  }
}

// --- K1: fused NCA step.
// MASKED=1: input is the previous step's unmasked x-tilde + prelife plane;
// the life mask is applied on the fly during staging (fuses old step2).
// MASKED=0: input is the raw initial state (step 0).
// 8x8 pixel tile; 4 waves each own 32 hidden units; all-wave reduce+write.
template <int MASKED>
__global__ __launch_bounds__(256, 2) void nca_step1(
    const float* __restrict__ xin, const float* __restrict__ plin,
    const float* __restrict__ pw, const float* __restrict__ w1t,
    const float* __restrict__ b1, const float* __restrict__ w2,
    float* __restrict__ xtld, float* __restrict__ plout,
    uint32_t k0, uint32_t k1)
{
  __shared__ float xt[CHN][TH + 2][TW + 2];
  __shared__ float At[TH + 4][TW + 4];     // alpha with 2-halo (12x12)
  __shared__ float Lf[TH + 2][TW + 2];     // life for staged region (10x10)
  __shared__ float dbuf[4][64][17];        // stride 17: conflict-free

  const int tid = threadIdx.x;
  const int bx = blockIdx.x;        // tile col 0..15
  const int by = blockIdx.y;        // tile row 0..15
  const int b  = blockIdx.z;        // batch
  const int oh = by * TH, ow = bx * TW;
  const float* xb = xin + (size_t)b * PLANE;

  if (MASKED) {
    // phase A: stage unmasked alpha over 12x12, compute life for 10x10
    for (int i = tid; i < (TH + 4) * (TW + 4); i += 256) {
      int r = i / (TW + 4), cc = i % (TW + 4);
      int gh = oh + r - 2, gw = ow + cc - 2;
      float v = 0.f;
      if (gh >= 0 && gh < HH && gw >= 0 && gw < WW)
        v = xb[(3 * HH + gh) * WW + gw];
      At[r][cc] = v;
    }
    __syncthreads();
    for (int i = tid; i < (TH + 2) * (TW + 2); i += 256) {
      int r = i / (TW + 2), cc = i % (TW + 2);
      int gh = oh + r - 1, gw = ow + cc - 1;
      float life = 0.f;
      if (gh >= 0 && gh < HH && gw >= 0 && gw < WW) {
        float m = At[r][cc];
        m = fmaxf(m, At[r][cc + 1]); m = fmaxf(m, At[r][cc + 2]);
        m = fmaxf(m, At[r + 1][cc]); m = fmaxf(m, At[r + 1][cc + 1]);
        m = fmaxf(m, At[r + 1][cc + 2]);
        m = fmaxf(m, At[r + 2][cc]); m = fmaxf(m, At[r + 2][cc + 1]);
        m = fmaxf(m, At[r + 2][cc + 2]);
        if (m > 0.1f && plin[b * NPIX + gh * WW + gw] > 0.5f) life = 1.f;
      }
      Lf[r][cc] = life;
    }
    __syncthreads();
  }

  // phase B: stage 16 channels x 10x10, applying life mask if MASKED
  for (int i = tid; i < CHN * (TH + 2) * (TW + 2); i += 256) {
    int c  = i / ((TH + 2) * (TW + 2));
    int r  = (i / (TW + 2)) % (TH + 2);
    int cc = i % (TW + 2);
    int gh = oh + r - 1, gw = ow + cc - 1;
    float v = 0.f;
    if (gh >= 0 && gh < HH && gw >= 0 && gw < WW) {
      v = xb[(c * HH + gh) * WW + gw];
      if (MASKED) v *= Lf[r][cc];
    }
    xt[c][r][cc] = v;
  }
  __syncthreads();

  const int wv   = __builtin_amdgcn_readfirstlane((int)threadIdx.x) >> 6;
  const int lane = tid & 63;
  const int pr = lane >> 3, pc = lane & 7;   // pixel within 8x8 tile
  const int jbase = wv * 32;                 // hidden-dim quarter (uniform)

  // comb = [x(16) ; p(32)]: depthwise sobel pair per channel
  float comb[48];
  float premax = -1e30f;
  #pragma unroll
  for (int c = 0; c < CHN; ++c) {
    float n[9];
    #pragma unroll
    for (int dy = 0; dy < 3; ++dy)
      #pragma unroll
      for (int dx = 0; dx < 3; ++dx)
        n[dy * 3 + dx] = xt[c][pr + dy][pc + dx];
    comb[c] = n[4];
    float p0 = 0.f, p1 = 0.f;
    #pragma unroll
    for (int i = 0; i < 9; ++i) {
      p0 = fmaf(pw[(2 * c) * 9 + i], n[i], p0);
      p1 = fmaf(pw[(2 * c + 1) * 9 + i], n[i], p1);
    }
    comb[16 + 2 * c] = p0;
    comb[17 + 2 * c] = p1;
    if (c == 3) {
      float m = n[0];
      #pragma unroll
      for (int i = 1; i < 9; ++i) m = fmaxf(m, n[i]);
      premax = m;
    }
  }
  // pin comb into VGPRs (R1: allocator demoted it at VGPR_Count=40)
  #pragma unroll
  for (int k = 0; k < 48; ++k) asm volatile("" : "+v"(comb[k]));

  // this wave: j in [jbase, jbase+32), unrolled x4 for ILP
  float delta[16];
  #pragma unroll
  for (int c = 0; c < 16; ++c) delta[c] = 0.f;
  for (int jj = 0; jj < 32; jj += 4) {
    const int j0 = jbase + jj;
    const float* wr = w1t + j0 * 48;
    float a0 = b1[j0], a1 = b1[j0 + 1], a2 = b1[j0 + 2], a3 = b1[j0 + 3];
    #pragma unroll
    for (int k = 0; k < 48; ++k) {
      const float ck = comb[k];
      a0 = fmaf(ck, wr[k], a0);
      a1 = fmaf(ck, wr[k + 48], a1);
      a2 = fmaf(ck, wr[k + 96], a2);
      a3 = fmaf(ck, wr[k + 144], a3);
    }
    a0 = fmaxf(a0, 0.f); a1 = fmaxf(a1, 0.f);
    a2 = fmaxf(a2, 0.f); a3 = fmaxf(a3, 0.f);
    const float* w20 = w2 + j0 * 16;
    #pragma unroll
    for (int c = 0; c < 16; ++c) {
      float d = delta[c];
      d = fmaf(a0, w20[c], d);
      d = fmaf(a1, w20[16 + c], d);
      d = fmaf(a2, w20[32 + c], d);
      d = fmaf(a3, w20[48 + c], d);
      delta[c] = d;
    }
  }

  // all-wave reduce: every wave publishes its 16 partials...
  #pragma unroll
  for (int c = 0; c < 16; ++c) dbuf[wv][lane][c] = delta[c];
  __syncthreads();

  // ...then owns 4 output channels (cb..cb+3)
  const int cb = wv * 4;
  const int gh = oh + pr, gw = ow + pc;
  const int gidx = gh * WW + gw;

  uint32_t o0, o1;
  tf2x32(k0, k1, 0u, (uint32_t)(b * NPIX + gidx), &o0, &o1);
  const uint32_t bits = o0 ^ o1;
  const float u = (((bits >> 31) == 0u) && (comb[3] > 0.1f)) ? 1.f : 0.f;

  float* qb = xtld + (size_t)b * PLANE;
  #pragma unroll
  for (int c2 = 0; c2 < 4; ++c2) {
    const int c = cb + c2;
    float s = delta[c];
    #pragma unroll
    for (int t = 0; t < 4; ++t)
      if (t != wv) s += dbuf[t][lane][c];
    qb[c * NPIX + gidx] = fmaf(s, u, comb[c]);
  }
  if (wv == 0) plout[b * NPIX + gidx] = (premax > 0.1f) ? 1.f : 0.f;
}

// --- final: materialize d_out = xtld * (prelife & living(xtld))
__global__ __launch_bounds__(256) void nca_final(
    const float* __restrict__ xtld, const float* __restrict__ prelife,
    float* __restrict__ xout)
{
  const int g = blockIdx.x * 256 + threadIdx.x;   // 0..32767
  const int b = g >> 14, hw = g & (NPIX - 1);
  const int h = hw >> 7, w = hw & 127;
  const float* qb = xtld + (size_t)b * PLANE;
  const float* ap = qb + 3 * NPIX;
  float m = -1e30f;
  for (int dy = -1; dy <= 1; ++dy) {
    int hh = h + dy; if (hh < 0 || hh >= HH) continue;
    for (int dx = -1; dx <= 1; ++dx) {
      int ww2 = w + dx; if (ww2 < 0 || ww2 >= WW) continue;
      m = fmaxf(m, ap[hh * WW + ww2]);
    }
  }
  const float life = (m > 0.1f && prelife[g] > 0.5f) ? 1.f : 0.f;
  float* ob = xout + (size_t)b * PLANE;
  #pragma unroll
  for (int c = 0; c < CHN; ++c)
    ob[c * NPIX + hw] = qb[c * NPIX + hw] * life;
}

extern "C" void kernel_launch(void* const* d_in, const int* in_sizes, int n_in,
                              void* d_out, int out_size, void* d_ws, size_t ws_size,
                              hipStream_t stream) {
  (void)in_sizes; (void)n_in; (void)out_size; (void)ws_size;
  const float* x  = (const float*)d_in[0];
  const float* pw = (const float*)d_in[1];
  const float* w1 = (const float*)d_in[2];
  const float* b1 = (const float*)d_in[3];
  const float* w2 = (const float*)d_in[4];

  float* out = (float*)d_out;
  float* ws  = (float*)d_ws;
  // ping-pong state: blocks read neighbor halos, so src and dst must differ
  float* xbuf[2] = { ws, ws + 2 * PLANE };                    // unmasked x-tilde
  float* pbuf[2] = { ws + 4 * PLANE, ws + 4 * PLANE + 2 * NPIX };  // prelife
  float* w1t     = ws + 4 * PLANE + 4 * NPIX;                 // 6144 floats

  prep_w1t<<<(48 * 128 + 255) / 256, 256, 0, stream>>>(w1, w1t);

  // host-side key schedule: key(42) split into 64 step keys (partitionable)
  uint32_t key0[STEPS], key1[STEPS];
  for (uint32_t s = 0; s < STEPS; ++s)
    tf2x32(0u, 42u, 0u, s, &key0[s], &key1[s]);

  dim3 g1(WW / TW, HH / TH, 2);   // 16 x 16 x 2 = 512 blocks
  // step 0: raw input, no mask to apply
  nca_step1<0><<<g1, 256, 0, stream>>>(x, nullptr, pw, w1t, b1, w2,
                                       xbuf[0], pbuf[0], key0[0], key1[0]);
  for (int s = 1; s < STEPS; ++s) {
    const int pv = (s - 1) & 1, cu = s & 1;
    nca_step1<1><<<g1, 256, 0, stream>>>(xbuf[pv], pbuf[pv], pw, w1t, b1, w2,
                                         xbuf[cu], pbuf[cu], key0[s], key1[s]);
  }
  // final mask application into d_out (last step wrote parity (STEPS-1)&1)
  const int lf = (STEPS - 1) & 1;
  nca_final<<<(2 * NPIX) / 256, 256, 0, stream>>>(xbuf[lf], pbuf[lf], out);
}